// Round 8
// baseline (928.115 us; speedup 1.0000x reference)
//
#include <hip/hip_runtime.h>

#define HID 256
#define TLEN 1024
#define BATCH 128

typedef _Float16 half2_t __attribute__((ext_vector_type(2)));
typedef int i32x4 __attribute__((ext_vector_type(4)));

__device__ __forceinline__ float fexp2(float x) { return __builtin_amdgcn_exp2f(x); }
__device__ __forceinline__ float frcp(float x)  { return __builtin_amdgcn_rcpf(x); }
__device__ __forceinline__ float fast_sigmoid(float x) {
  return frcp(1.0f + fexp2(-1.442695040888963f * x));
}
__device__ __forceinline__ float fast_tanh(float x) {
  float e = fexp2(2.885390081777927f * x);
  return 1.0f - 2.0f * frcp(e + 1.0f);
}
__device__ __forceinline__ float dot2acc(half2_t a, half2_t b, float c) {
  return __builtin_amdgcn_fdot2(a, b, c, false);   // v_dot2_f32_f16
}

#if defined(__has_builtin) && __has_builtin(__builtin_amdgcn_sdot4)
#define SDOT4(a, b, c) __builtin_amdgcn_sdot4((int)(a), (int)(b), (c), false)
#else
__device__ __forceinline__ int SDOT4(int a, int b, int c) {
#pragma unroll
  for (int e = 0; e < 4; ++e)
    c += ((a << (24 - 8 * e)) >> 24) * ((b << (24 - 8 * e)) >> 24);
  return c;
}
#endif

// DPP (VALU pipe). Verified on this HW R6-R12.
#define DPP_ADD_F(var, ctrl, rmask)                                            \
  var += __builtin_bit_cast(float, __builtin_amdgcn_update_dpp(                \
      0, __builtin_bit_cast(int, var), (ctrl), (rmask), 0xf, true))
#define DPP_ADD_I(var, ctrl, rmask)                                            \
  var += __builtin_amdgcn_update_dpp(0, (var), (ctrl), (rmask), 0xf, true)

__device__ __forceinline__ float wave_sum63_f(float p) {
  DPP_ADD_F(p, 0x111, 0xf);
  DPP_ADD_F(p, 0x112, 0xf);
  DPP_ADD_F(p, 0x114, 0xf);
  DPP_ADD_F(p, 0x118, 0xf);
  DPP_ADD_F(p, 0x142, 0xa);
  DPP_ADD_F(p, 0x143, 0xc);   // -> lane63 has wave total
  return p;
}
__device__ __forceinline__ int wave_sum63_i(int p) {
  DPP_ADD_I(p, 0x111, 0xf);
  DPP_ADD_I(p, 0x112, 0xf);
  DPP_ADD_I(p, 0x114, 0xf);
  DPP_ADD_I(p, 0x118, 0xf);
  DPP_ADD_I(p, 0x142, 0xa);
  DPP_ADD_I(p, 0x143, 0xc);   // -> lane63 has wave total (exact, int)
  return p;
}

// ---- prep: per-row i8 quant of W_hh (768x256), row-major wq[row*16 + c]
// (c = 16-byte k-chunk, bytes little-endian = ascending k); plus i8 pack of
// Wb_h with folded scale so hWb = sdot_total * wbscale.
__global__ void quant_whh(const float* __restrict__ W_hh,
                          const float* __restrict__ Wb_h,
                          uint4* __restrict__ wq,
                          float* __restrict__ scales,
                          unsigned* __restrict__ wbq,
                          float* __restrict__ wbscale) {
  const int r = blockIdx.x * 256 + threadIdx.x;   // 0..1023
  if (r < 768) {
    const float* row = W_hh + (size_t)r * HID;
    float amax = 0.0f;
    for (int k = 0; k < HID; ++k) amax = fmaxf(amax, fabsf(row[k]));
    amax = fmaxf(amax, 1e-20f);
    scales[r] = amax / 127.0f;
    const float inv = 127.0f / amax;
    for (int c = 0; c < 16; ++c) {
      unsigned w[4];
#pragma unroll
      for (int u = 0; u < 4; ++u) {
        unsigned bb = 0;
#pragma unroll
        for (int e = 0; e < 4; ++e) {
          int qv = (int)rintf(row[16 * c + 4 * u + e] * inv);
          bb |= (unsigned)(qv & 0xff) << (8 * e);
        }
        w[u] = bb;
      }
      wq[(size_t)r * 16 + c] = uint4{w[0], w[1], w[2], w[3]};
    }
  } else if (r < 832) {
    // threads 768..831: pack Wb_h word (r-768); amax computed redundantly
    float amax = 0.0f;
    for (int k = 0; k < HID; ++k) amax = fmaxf(amax, fabsf(Wb_h[k]));
    amax = fmaxf(amax, 1e-20f);
    const float inv = 127.0f / amax;
    const int i = r - 768;
    unsigned bb = 0;
#pragma unroll
    for (int e = 0; e < 4; ++e) {
      int qv = (int)rintf(Wb_h[4 * i + e] * inv);
      bb |= (unsigned)(qv & 0xff) << (8 * e);
    }
    wbq[i] = bb;
    if (i == 0) wbscale[0] = (amax / 127.0f) * (1.0f / 127.0f);
  }
}

// R21: MFMA-i8 matvec via the OFFICIAL BUILTIN (R20's inline asm lacked the
// mandatory VALU<->MFMA wait-states -- hazard recognizer doesn't parse asm
// text -> sporadic stale-operand garbage, the observed nondeterministic
// small-error failure). __builtin_amdgcn_mfma_i32_16x16x64_i8 lets the
// compiler own hazards/scheduling and park the 192 B-fragment dwords in
// AGPRs (MFMA reads them directly; same allocation pattern as the proven
// 824us baseline at waves_per_eu(1,1)).
// Layout hedges kept: h broadcast into all 16 A-rows (row map irrelevant,
// all D rows identical); A and B share contiguous-k packing (internal k-perm
// cancels by symmetry); extraction via HW-verified C/D map (col=lane&15,
// reg 0, lanes 0-15). Integer-exact => absmax must equal 0.00390625 exactly.
__global__
__attribute__((amdgpu_flat_work_group_size(256, 256)))
__attribute__((amdgpu_waves_per_eu(1, 1)))
void momgru_persistent(const float* __restrict__ x,
                       const float* __restrict__ W_ih,
                       const float* __restrict__ b_ih,
                       const float* __restrict__ b_hh,
                       const float* __restrict__ Wb_x,
                       const float* __restrict__ b_beta,
                       const float* __restrict__ s_ptr,
                       const float* __restrict__ W_head,
                       const float* __restrict__ b_head,
                       const uint4* __restrict__ wq,
                       const float* __restrict__ scales,
                       const unsigned* __restrict__ wbq,
                       const float* __restrict__ wbscale,
                       float* __restrict__ out)  // [0,128) head, [128,128+B*T) betas
{
  const int b    = blockIdx.x;
  const int tid  = threadIdx.x;   // == dim d
  const int lane = tid & 63;
  const int wv   = tid >> 6;      // 0..3
  const int l15  = lane & 15;
  const int lg   = lane >> 4;     // 16-lane group 0..3

  __shared__ __align__(16) unsigned hq[2][64];  // h as i8, double-buffered
  __shared__ int   gm[3 * HID];                 // matvec results (wave-local slices)
  __shared__ float red[4];                      // head reduce

  // ---- B-fragments: tile t = gate*4+i covers out-rows gate*256+64*wv+16*i
  // +0..15; chunk c covers k = 64c..64c+63. Lane holds col=l15's row, k-bytes
  // 16*lg..16*lg+15 = wq[row*16 + 4c + lg]. ----
  i32x4 bw[12][4];
#pragma unroll
  for (int t = 0; t < 12; ++t) {
    const int gate = t >> 2, i = t & 3;
    const int row = gate * 256 + 64 * wv + 16 * i + l15;
#pragma unroll
    for (int c = 0; c < 4; ++c)
      bw[t][c] = *reinterpret_cast<const i32x4*>(&wq[(size_t)row * 16 + 4 * c + lg]);
  }

  // ---- per-thread constants (s pre-folded into input projection) ----
  const float sv = s_ptr[0];
  const half2_t wih_r = half2_t{(_Float16)(sv * W_ih[2 * tid]),             (_Float16)(sv * W_ih[2 * tid + 1])};
  const half2_t wih_z = half2_t{(_Float16)(sv * W_ih[2 * (HID + tid)]),     (_Float16)(sv * W_ih[2 * (HID + tid) + 1])};
  const half2_t wih_n = half2_t{(_Float16)(sv * W_ih[2 * (2 * HID + tid)]), (_Float16)(sv * W_ih[2 * (2 * HID + tid) + 1])};
  const float bih_r = sv * b_ih[tid], bih_z = sv * b_ih[HID + tid], bih_n = sv * b_ih[2 * HID + tid];
  const float bhh_r = b_hh[tid], bhh_z = b_hh[HID + tid], bhh_n = b_hh[2 * HID + tid];
  const float sc_r = scales[tid] * (1.0f / 127.0f);
  const float sc_z = scales[HID + tid] * (1.0f / 127.0f);
  const float sc_n = scales[2 * HID + tid] * (1.0f / 127.0f);
  const half2_t wbx2 = half2_t{(_Float16)Wb_x[0], (_Float16)Wb_x[1]};  // uniform
  const float bbeta = b_beta[0];
  const unsigned wbq_l = wbq[lane];       // Wb_h i8, dims 4*lane..4*lane+3
  const float wbsc = wbscale[0];          // folded (amax/127)*(1/127)

  // ---- init ----
  if (tid < 128) reinterpret_cast<unsigned*>(hq)[tid] = 0u;
  if (tid < 4) red[tid] = 0.0f;
  float h_old = 0.0f, vr = 0.0f, vz = 0.0f, vn = 0.0f;
  float* betas = out + BATCH;
  const float2* xg2 = reinterpret_cast<const float2*>(x + (size_t)b * TLEN * 2);
  float2 xv = xg2[0];
  __syncthreads();

  int cur = 0;
  for (int t = 0; t < TLEN; ++t) {
    // ---- A) A-fragments: broadcast h into all 16 rows (lane gets k-bytes
    //         16*lg..16*lg+15 of chunk c, independent of l15) ----
    const char* hqb = reinterpret_cast<const char*>(hq[cur]);
    const i32x4 af0 = *reinterpret_cast<const i32x4*>(hqb + 0   + 16 * lg);
    const i32x4 af1 = *reinterpret_cast<const i32x4*>(hqb + 64  + 16 * lg);
    const i32x4 af2 = *reinterpret_cast<const i32x4*>(hqb + 128 + 16 * lg);
    const i32x4 af3 = *reinterpret_cast<const i32x4*>(hqb + 192 + 16 * lg);

    // ---- B) per-wave hWb from h_{t-1} i8 words (issues under the mfmas) ----
    const unsigned hw_l = reinterpret_cast<const unsigned*>(hq[cur])[lane];
    int hwb_i = SDOT4(hw_l, wbq_l, 0);
    hwb_i = wave_sum63_i(hwb_i);

    // ---- C) 48 mfma: 12 tiles x 4 k-chunks, accumulate over chunks ----
    i32x4 acc[12];
#pragma unroll
    for (int tt = 0; tt < 12; ++tt) acc[tt] = i32x4{0, 0, 0, 0};
#pragma unroll
    for (int tt = 0; tt < 12; ++tt)
      acc[tt] = __builtin_amdgcn_mfma_i32_16x16x64_i8(af0, bw[tt][0], acc[tt], 0, 0, 0);
#pragma unroll
    for (int tt = 0; tt < 12; ++tt)
      acc[tt] = __builtin_amdgcn_mfma_i32_16x16x64_i8(af1, bw[tt][1], acc[tt], 0, 0, 0);
#pragma unroll
    for (int tt = 0; tt < 12; ++tt)
      acc[tt] = __builtin_amdgcn_mfma_i32_16x16x64_i8(af2, bw[tt][2], acc[tt], 0, 0, 0);
#pragma unroll
    for (int tt = 0; tt < 12; ++tt)
      acc[tt] = __builtin_amdgcn_mfma_i32_16x16x64_i8(af3, bw[tt][3], acc[tt], 0, 0, 0);

    // ---- D) beta + momentum (overlaps mfma pipe) ----
    const float hWb = (float)__builtin_amdgcn_readlane(hwb_i, 63) * wbsc;
    const half2_t x2 = half2_t{(_Float16)xv.x, (_Float16)xv.y};
    xv = xg2[(t + 1 < TLEN) ? t + 1 : t];
    const float beta = fast_sigmoid(dot2acc(x2, wbx2, hWb + bbeta));
    vr = beta * vr + dot2acc(x2, wih_r, bih_r);
    vz = beta * vz + dot2acc(x2, wih_z, bih_z);
    vn = beta * vn + dot2acc(x2, wih_n, bih_n);

    // ---- E) extract D row 0 (lanes 0-15, reg 0; all rows identical due to
    //         broadcast-A) -> wave-local LDS slice ----
    if (lane < 16) {
#pragma unroll
      for (int tt = 0; tt < 12; ++tt) {
        const int gate = tt >> 2, i = tt & 3;
        gm[gate * 256 + 64 * wv + 16 * i + l15] = acc[tt][0];
      }
    }
    // within-wave write->read: DS ops complete in order per wave; the
    // compiler's lgkmcnt wait on the read covers the earlier writes.
    const int ar = gm[tid];
    const int az = gm[HID + tid];
    const int an = gm[2 * HID + tid];

    // ---- F) gates ----
    const float r = fast_sigmoid(vr + (float)ar * sc_r + bhh_r);
    const float z = fast_sigmoid(vz + (float)az * sc_z + bhh_z);
    const float n = fast_tanh(vn + r * ((float)an * sc_n + bhh_n));
    h_old = (1.0f - z) * n + z * h_old;

    // ---- G) quantize h -> i8, one byte store per thread ----
    const int nxt = cur ^ 1;
    const int qb = (int)rintf(h_old * 127.0f);
    reinterpret_cast<unsigned char*>(hq[nxt])[tid] = (unsigned char)(qb & 0xff);

    if (tid == 0) betas[(size_t)b * TLEN + t] = beta;

    __syncthreads();
    cur = nxt;
  }

  // ---- head ----
  float hp = h_old * W_head[tid];
  hp = wave_sum63_f(hp);
  if (lane == 63) red[wv] = hp;
  __syncthreads();
  if (tid == 0)
    out[b] = ((red[0] + red[1]) + (red[2] + red[3])) + b_head[0];
}

extern "C" void kernel_launch(void* const* d_in, const int* in_sizes, int n_in,
                              void* d_out, int out_size, void* d_ws, size_t ws_size,
                              hipStream_t stream) {
  const float* x      = (const float*)d_in[0];
  const float* W_ih   = (const float*)d_in[1];
  const float* W_hh   = (const float*)d_in[2];
  const float* b_ih   = (const float*)d_in[3];
  const float* b_hh   = (const float*)d_in[4];
  const float* Wb_x   = (const float*)d_in[5];
  const float* Wb_h   = (const float*)d_in[6];
  const float* b_beta = (const float*)d_in[7];
  const float* s      = (const float*)d_in[8];
  const float* W_head = (const float*)d_in[9];
  const float* b_head = (const float*)d_in[10];
  float* out = (float*)d_out;

  char* wsb = (char*)d_ws;
  uint4*    wq      = (uint4*)wsb;                 // 768*16*16 = 196608 B
  float*    scales  = (float*)(wsb + 196608);      // 768*4 = 3072 B
  unsigned* wbq     = (unsigned*)(wsb + 199680);   // 64*4 = 256 B
  float*    wbscale = (float*)(wsb + 199936);      // 4 B

  quant_whh<<<dim3(4), dim3(256), 0, stream>>>(W_hh, Wb_h, wq, scales, wbq, wbscale);
  momgru_persistent<<<dim3(BATCH), dim3(256), 0, stream>>>(
      x, W_ih, b_ih, b_hh, Wb_x, b_beta, s, W_head, b_head,
      (const uint4*)wq, (const float*)scales, (const unsigned*)wbq,
      (const float*)wbscale, out);
}